// Round 1
// baseline (61.822 us; speedup 1.0000x reference)
//
#include <hip/hip_runtime.h>
#include <math.h>

#define N_RAYS 86400
#define N_SAMP 287

__global__ __launch_bounds__(256) void nerf_depth_kernel(
    const float* __restrict__ rays_o,
    const float* __restrict__ rays_d,
    const float* __restrict__ voxel,
    float* __restrict__ depth_out,
    float stepf, float delta)
{
    const int lane = threadIdx.x & 63;
    const int ray  = blockIdx.x * (blockDim.x >> 6) + (threadIdx.x >> 6);
    if (ray >= N_RAYS) return;

    const float ox = rays_o[3*ray+0], oy = rays_o[3*ray+1], oz = rays_o[3*ray+2];
    const float dx = rays_d[3*ray+0], dy = rays_d[3*ray+1], dz = rays_d[3*ray+2];

    const float minx = -40.0f, miny = -40.0f, minz = -1.0f;
    const float maxx =  40.0f, maxy =  40.0f, maxz =  5.4f;
    const float rngx = maxx - minx;           // 80.0f
    const float rngy = maxy - miny;           // 80.0f
    const float rngz = maxz - minz;           // fl32(6.4)

    float T = 1.0f;          // running transmittance (wave-uniform value per lane)
    float depth_acc = 0.0f;  // per-lane partial depth

    for (int c = 0; c * 64 < N_SAMP; ++c) {
        const int  s     = c * 64 + lane;
        const bool valid = (s < N_SAMP);
        const float z  = __fmul_rn(stepf, (float)s);
        // match numpy: separate mul + add, no FMA contraction (mask is strict-compare sensitive)
        const float px = __fadd_rn(ox, __fmul_rn(dx, z));
        const float py = __fadd_rn(oy, __fmul_rn(dy, z));
        const float pz = __fadd_rn(oz, __fmul_rn(dz, z));
        const bool inside = !((px < minx) | (px > maxx) |
                              (py < miny) | (py > maxy) |
                              (pz < minz) | (pz > maxz));
        const bool inb = valid && inside;
        // ray starts inside a convex box: first all-outside chunk => done forever
        if (__ballot(inb) == 0ULL) break;

        float alpha = 0.0f;
        if (inb) {
            // align_corners=True trilinear sample with clamping
            float ux = (px - minx) / rngx;
            float uy = (py - miny) / rngy;
            float uz = (pz - minz) / rngz;
            float ix = fminf(fmaxf(ux * 199.0f, 0.0f), 199.0f);
            float iy = fminf(fmaxf(uy * 199.0f, 0.0f), 199.0f);
            float iz = fminf(fmaxf(uz * 15.0f,  0.0f), 15.0f);
            float fx0 = floorf(ix), fy0 = floorf(iy), fz0 = floorf(iz);
            int x0 = (int)fminf(fmaxf(fx0, 0.0f), 198.0f);
            int y0 = (int)fminf(fmaxf(fy0, 0.0f), 198.0f);
            int z0 = (int)fminf(fmaxf(fz0, 0.0f), 14.0f);
            float fx = ix - (float)x0;
            float fy = iy - (float)y0;
            float fz = iz - (float)z0;
            const float* base = voxel + ((x0 * 200 + y0) * 16 + z0);
            float c000 = base[0],    c001 = base[1];
            float c010 = base[16],   c011 = base[17];
            float c100 = base[3200], c101 = base[3201];
            float c110 = base[3216], c111 = base[3217];
            float gx = 1.0f - fx, gy = 1.0f - fy, gz = 1.0f - fz;
            float d = c000*(gx*gy*gz) + c001*(gx*gy*fz)
                    + c010*(gx*fy*gz) + c011*(gx*fy*fz)
                    + c100*(fx*gy*gz) + c101*(fx*gy*fz)
                    + c110*(fx*fy*gz) + c111*(fx*fy*fz);
            // jax.nn.softplus(x) = max(x,0) + log1p(exp(-|x|))
            float sp = fmaxf(d, 0.0f) + log1pf(expf(-fabsf(d)));
            alpha = 1.0f - expf(-(sp * delta));
        }

        // g = clip(1 - alpha, 1e-10); masked / invalid lanes contribute g = 1
        float g = fmaxf(1.0f - alpha, 1e-10f);

        // inclusive prefix product across the 64 lanes
        float P = g;
        #pragma unroll
        for (int off = 1; off < 64; off <<= 1) {
            float t = __shfl_up(P, off, 64);
            if (lane >= off) P *= t;
        }
        // exclusive prefix (transmittance up to but excluding this sample)
        float E = __shfl_up(P, 1, 64);
        if (lane == 0) E = 1.0f;

        depth_acc += alpha * (T * E) * z;
        T *= __shfl(P, 63, 64);   // fold in whole-chunk product
    }

    // wave-wide sum of per-lane depth contributions
    #pragma unroll
    for (int off = 32; off > 0; off >>= 1)
        depth_acc += __shfl_xor(depth_acc, off, 64);
    if (lane == 0) depth_out[ray] = depth_acc;
}

extern "C" void kernel_launch(void* const* d_in, const int* in_sizes, int n_in,
                              void* d_out, int out_size, void* d_ws, size_t ws_size,
                              hipStream_t stream) {
    (void)in_sizes; (void)n_in; (void)d_ws; (void)ws_size; (void)out_size;
    const float* rays_o = (const float*)d_in[0];
    const float* rays_d = (const float*)d_in[1];
    const float* voxel  = (const float*)d_in[2];
    float* out = (float*)d_out;

    // Reproduce numpy's constant chain in float32:
    // VOXEL_SIZE = (prod(f32(XYZ_MAX-XYZ_MIN)) / 640000) ** (1/3); step = f32(0.5*VOXEL_SIZE)
    float rngz  = 5.4f - (-1.0f);
    float prod  = (80.0f * 80.0f) * rngz;
    float ratio = prod / 640000.0f;
    float stepf = (float)(0.5 * pow((double)ratio, 1.0 / 3.0));   // == 0.2f
    float delta = stepf * 286.0f - stepf * 285.0f;                // zval[-1]-zval[-2]

    const int waves_per_block = 4;                 // 256 threads
    const int blocks = (N_RAYS + waves_per_block - 1) / waves_per_block;
    nerf_depth_kernel<<<blocks, 256, 0, stream>>>(rays_o, rays_d, voxel, out, stepf, delta);
}

// Round 2
// 28.547 us; speedup vs baseline: 2.1656x; 2.1656x over previous
//
#include <hip/hip_runtime.h>
#include <math.h>

#define N_RAYS 86400
#define N_SAMP 287
#define GRP_W  16          // lanes per ray (4 rays per wave)
#define N_CHUNK ((N_SAMP + GRP_W - 1) / GRP_W)   // 18
#define LOG2E 1.4426950408889634f

__global__ __launch_bounds__(256) void nerf_depth_kernel(
    const float* __restrict__ rays_o,
    const float* __restrict__ rays_d,
    const float* __restrict__ voxel,
    float* __restrict__ depth_out,
    float stepf, float delta)
{
    const int lane = threadIdx.x & 63;
    const int sub  = lane & (GRP_W - 1);     // lane within ray-group
    const int grp  = lane >> 4;              // ray-group within wave (0..3)
    const int wave = (blockIdx.x * blockDim.x + threadIdx.x) >> 6;
    const int ray  = wave * 4 + grp;         // 86400 = 4 * 21600, no tail
    if (ray >= N_RAYS) return;

    const float ox = rays_o[3*ray+0], oy = rays_o[3*ray+1], oz = rays_o[3*ray+2];
    const float dx = rays_d[3*ray+0], dy = rays_d[3*ray+1], dz = rays_d[3*ray+2];

    // idx = clamp(((p - min) / rng) * (size-1), 0, size-1)  folded to fma:
    const float cx1 = 199.0f / 80.0f;                  const float cx0 = 40.0f * cx1;
    const float cy1 = cx1;                             const float cy0 = cx0;
    const float cz1 = 15.0f / (5.4f - (-1.0f));        const float cz0 = 1.0f * cz1;
    const float negdelta = -delta;

    float T = 1.0f;          // group-uniform running transmittance
    float depth_acc = 0.0f;  // per-lane partial depth
    bool  done = false;      // group-uniform

    for (int c = 0; c < N_CHUNK; ++c) {
        const int  s     = c * GRP_W + sub;
        const bool valid = (s < N_SAMP);
        const float z  = __fmul_rn(stepf, (float)s);
        // mask must stay bit-exact vs numpy: separate mul + add, strict compares
        const float px = __fadd_rn(ox, __fmul_rn(dx, z));
        const float py = __fadd_rn(oy, __fmul_rn(dy, z));
        const float pz = __fadd_rn(oz, __fmul_rn(dz, z));
        const bool inside = !((px < -40.0f) | (px > 40.0f) |
                              (py < -40.0f) | (py > 40.0f) |
                              (pz < -1.0f)  | (pz > 5.4f));
        const bool inb = (!done) && valid && inside;

        // group-level termination: ray started inside a convex box, so an
        // all-outside chunk means outside forever
        const unsigned long long bal = __ballot(inb);
        if (((unsigned)(bal >> (grp * GRP_W)) & 0xFFFFu) == 0u) done = true;
        if (__all(done)) break;

        float alpha = 0.0f;
        if (inb) {
            float ix = fminf(fmaxf(__builtin_fmaf(px, cx1, cx0), 0.0f), 199.0f);
            float iy = fminf(fmaxf(__builtin_fmaf(py, cy1, cy0), 0.0f), 199.0f);
            float iz = fminf(fmaxf(__builtin_fmaf(pz, cz1, cz0), 0.0f), 15.0f);
            int x0 = min((int)ix, 198);
            int y0 = min((int)iy, 198);
            int z0 = min((int)iz, 14);
            float fx = ix - (float)x0;
            float fy = iy - (float)y0;
            float fz = iz - (float)z0;
            const float* base = voxel + ((x0 * 200 + y0) * 16 + z0);
            float c000 = base[0],    c001 = base[1];
            float c010 = base[16],   c011 = base[17];
            float c100 = base[3200], c101 = base[3201];
            float c110 = base[3216], c111 = base[3217];
            // nested lerp (7 lerps = 14 fma-class ops)
            float c00 = c000 + fz * (c001 - c000);
            float c01 = c010 + fz * (c011 - c010);
            float c10 = c100 + fz * (c101 - c100);
            float c11 = c110 + fz * (c111 - c110);
            float c0  = c00 + fy * (c01 - c00);
            float c1  = c10 + fy * (c11 - c10);
            float d   = c0  + fx * (c1  - c0);
            // alpha = 1 - exp(-delta*softplus(d)) = 1 - 2^(-delta*log2(1+2^(d*log2e)))
            float e2 = exp2f(d * LOG2E);               // exp(d), |d| small => no overflow
            float lg = __log2f(1.0f + e2);             // log2(1+e^d) = softplus(d)*log2e
            alpha = 1.0f - exp2f(negdelta * lg);
        }

        // g = clip(1 - alpha, 1e-10); masked/done lanes: g = 1
        float g = fmaxf(1.0f - alpha, 1e-10f);

        // inclusive prefix product across the 16-lane group
        float P = g;
        #pragma unroll
        for (int off = 1; off < GRP_W; off <<= 1) {
            float t = __shfl_up(P, off, GRP_W);
            if (sub >= off) P *= t;
        }
        float E = __shfl_up(P, 1, GRP_W);     // exclusive prefix
        if (sub == 0) E = 1.0f;

        depth_acc = __builtin_fmaf(alpha * z, T * E, depth_acc);
        T *= __shfl(P, GRP_W - 1, GRP_W);     // fold in whole-chunk product

        // transmittance cutoff: residual depth <= T * z_max = 1e-6 * 57.2
        if (T < 1e-6f) done = true;
    }

    // sum the 16 per-lane partials
    #pragma unroll
    for (int off = GRP_W / 2; off > 0; off >>= 1)
        depth_acc += __shfl_xor(depth_acc, off, GRP_W);
    if (sub == 0) depth_out[ray] = depth_acc;
}

extern "C" void kernel_launch(void* const* d_in, const int* in_sizes, int n_in,
                              void* d_out, int out_size, void* d_ws, size_t ws_size,
                              hipStream_t stream) {
    (void)in_sizes; (void)n_in; (void)d_ws; (void)ws_size; (void)out_size;
    const float* rays_o = (const float*)d_in[0];
    const float* rays_d = (const float*)d_in[1];
    const float* voxel  = (const float*)d_in[2];
    float* out = (float*)d_out;

    // numpy constant chain in float32: step == 0.2f
    float rngz  = 5.4f - (-1.0f);
    float prod  = (80.0f * 80.0f) * rngz;
    float ratio = prod / 640000.0f;
    float stepf = (float)(0.5 * pow((double)ratio, 1.0 / 3.0));
    float delta = stepf * 286.0f - stepf * 285.0f;

    // 4 rays per wave, 4 waves per block => 16 rays/block; 86400/16 = 5400 blocks
    const int blocks = N_RAYS / 16;
    nerf_depth_kernel<<<blocks, 256, 0, stream>>>(rays_o, rays_d, voxel, out, stepf, delta);
}

// Round 3
// 26.929 us; speedup vs baseline: 2.2958x; 1.0601x over previous
//
#include <hip/hip_runtime.h>
#include <math.h>

#define N_RAYS 86400
#define N_SAMP 287
#define GRP_W  16          // lanes per ray (4 rays per wave)
#define N_CHUNK ((N_SAMP + GRP_W - 1) / GRP_W)   // 18
#define LOG2E 1.4426950408889634f

// DPP row_shr:N prefix-shift within the 16-lane row; lanes that would read
// below the row edge get `old` (we pass the multiplicative identity 1.0f).
#define ROW_SHR_OLD1(x, N)                                                   \
    __int_as_float(__builtin_amdgcn_update_dpp(                              \
        0x3f800000 /*1.0f*/, __float_as_int(x), 0x110 | (N), 0xF, 0xF, false))

// ds_swizzle BitMode: new_lane = ((lane & and) | or) ^ xor  (per 32-lane half)
#define SWZ(x, pat) __int_as_float(__builtin_amdgcn_ds_swizzle(__float_as_int(x), (pat)))
#define SWZ_BCAST15 0x1F0   // and=0x10 or=0x0F xor=0  -> lane 15 of each 16-group
#define SWZ_XOR(m)  (((m) << 10) | 0x1F)   // lane ^= m within 32-half

__global__ __launch_bounds__(256) void nerf_depth_kernel(
    const float* __restrict__ rays_o,
    const float* __restrict__ rays_d,
    const float* __restrict__ voxel,
    float* __restrict__ depth_out,
    float stepf, float delta)
{
    const int lane = threadIdx.x & 63;
    const int sub  = lane & (GRP_W - 1);     // lane within ray-group
    const int grp  = lane >> 4;              // ray-group within wave (0..3)
    const int wave = (blockIdx.x * blockDim.x + threadIdx.x) >> 6;
    const int ray  = wave * 4 + grp;         // 86400 = 4 * 21600, exact

    const float ox = rays_o[3*ray+0], oy = rays_o[3*ray+1], oz = rays_o[3*ray+2];
    const float dx = rays_d[3*ray+0], dy = rays_d[3*ray+1], dz = rays_d[3*ray+2];

    // world -> grid-index, folded: idx = fma(p, c1, c0), then clamp
    const float cx1 = 199.0f / 80.0f;                  const float cx0 = 40.0f * cx1;
    const float cz1 = 15.0f / (5.4f - (-1.0f));        const float cz0 = 1.0f * cz1;
    const float negdelta = -delta;

    float T = 1.0f;          // group-uniform running transmittance
    float depth_acc = 0.0f;  // per-lane partial depth
    bool  done = false;      // group-uniform

    for (int c = 0; c < N_CHUNK; ++c) {
        const int  s     = c * GRP_W + sub;
        const bool valid = (s < N_SAMP);
        const float z  = __fmul_rn(stepf, (float)s);
        // mask must stay bit-exact vs numpy: separate mul + add, strict compares
        const float px = __fadd_rn(ox, __fmul_rn(dx, z));
        const float py = __fadd_rn(oy, __fmul_rn(dy, z));
        const float pz = __fadd_rn(oz, __fmul_rn(dz, z));
        // inside <=> !(|px|>40 | |py|>40 | pz<-1 | pz>5.4); abs is a free modifier
        const bool inside = !((fmaxf(fabsf(px), fabsf(py)) > 40.0f) |
                              (pz < -1.0f) | (pz > 5.4f));
        const bool inb = (!done) && valid && inside;

        // group termination: ray starts inside a convex box, so an all-outside
        // chunk means outside forever
        const unsigned long long bal = __ballot(inb);
        if (((unsigned)(bal >> (grp * GRP_W)) & 0xFFFFu) == 0u) done = true;
        if (__all(done)) break;

        float alpha = 0.0f, az = 0.0f;
        if (inb) {
            float ix = fminf(fmaxf(__builtin_fmaf(px, cx1, cx0), 0.0f), 199.0f);
            float iy = fminf(fmaxf(__builtin_fmaf(py, cx1, cx0), 0.0f), 199.0f);
            float iz = fminf(fmaxf(__builtin_fmaf(pz, cz1, cz0), 0.0f), 15.0f);
            int x0 = min((int)ix, 198);
            int y0 = min((int)iy, 198);
            int z0 = min((int)iz, 14);
            float fx = ix - (float)x0;
            float fy = iy - (float)y0;
            float fz = iz - (float)z0;
            // two plane bases so all 8 loads use small immediate offsets
            const float* ba = voxel + (y0 * 16 + z0);
            const float* bb = ba + x0 * 3200;        // x0-plane
            const float* bc = bb + 3200;             // (x0+1)-plane
            float c000 = bb[0],  c001 = bb[1];
            float c010 = bb[16], c011 = bb[17];
            float c100 = bc[0],  c101 = bc[1];
            float c110 = bc[16], c111 = bc[17];
            float c00 = c000 + fz * (c001 - c000);
            float c01 = c010 + fz * (c011 - c010);
            float c10 = c100 + fz * (c101 - c100);
            float c11 = c110 + fz * (c111 - c110);
            float c0  = c00 + fy * (c01 - c00);
            float c1  = c10 + fy * (c11 - c10);
            float d   = c0  + fx * (c1  - c0);
            // alpha = 1 - exp(-delta*softplus(d)) = 1 - 2^(-delta*log2(1+e^d))
            float e2 = exp2f(d * LOG2E);
            float lg = __log2f(1.0f + e2);
            alpha = 1.0f - exp2f(negdelta * lg);
            az = alpha * z;
        }

        // g = clip(1-alpha, 1e-10); masked/done lanes: g = 1  (clip never binds:
        // |d| <= ~6 so exp(-delta*sp) >> 1e-10, but keep for safety)
        float g = fmaxf(1.0f - alpha, 1e-10f);

        // inclusive prefix product across the 16-lane group via DPP row_shr
        float P = g;
        P *= ROW_SHR_OLD1(P, 1);
        P *= ROW_SHR_OLD1(P, 2);
        P *= ROW_SHR_OLD1(P, 4);
        P *= ROW_SHR_OLD1(P, 8);
        float E = ROW_SHR_OLD1(P, 1);      // exclusive prefix (lane0 -> 1.0)

        depth_acc = __builtin_fmaf(az, T * E, depth_acc);
        T *= SWZ(P, SWZ_BCAST15);          // whole-chunk product -> all 16 lanes

        // transmittance cutoff: residual depth <= T * z_max = 1e-6 * 57.4
        if (T < 1e-6f) done = true;
    }

    // sum the 16 per-lane partials (butterfly within the 16-lane group)
    depth_acc += SWZ(depth_acc, SWZ_XOR(1));
    depth_acc += SWZ(depth_acc, SWZ_XOR(2));
    depth_acc += SWZ(depth_acc, SWZ_XOR(4));
    depth_acc += SWZ(depth_acc, SWZ_XOR(8));
    if (sub == 0) depth_out[ray] = depth_acc;
}

extern "C" void kernel_launch(void* const* d_in, const int* in_sizes, int n_in,
                              void* d_out, int out_size, void* d_ws, size_t ws_size,
                              hipStream_t stream) {
    (void)in_sizes; (void)n_in; (void)d_ws; (void)ws_size; (void)out_size;
    const float* rays_o = (const float*)d_in[0];
    const float* rays_d = (const float*)d_in[1];
    const float* voxel  = (const float*)d_in[2];
    float* out = (float*)d_out;

    // numpy constant chain in float32: step == 0.2f
    float rngz  = 5.4f - (-1.0f);
    float prod  = (80.0f * 80.0f) * rngz;
    float ratio = prod / 640000.0f;
    float stepf = (float)(0.5 * pow((double)ratio, 1.0 / 3.0));
    float delta = stepf * 286.0f - stepf * 285.0f;

    // 4 rays/wave, 4 waves/block => 16 rays/block; 86400/16 = 5400 blocks
    const int blocks = N_RAYS / 16;
    nerf_depth_kernel<<<blocks, 256, 0, stream>>>(rays_o, rays_d, voxel, out, stepf, delta);
}